// Round 2
// baseline (381.802 us; speedup 1.0000x reference)
//
#include <hip/hip_runtime.h>
#include <math.h>

// Problem constants: N=4, L=2048, E=512, H=8, hd=64, FORECAST=8
// M = N*L = 8192 token rows.

#define NEGV -1e30f

typedef __bf16 bf16_t;
typedef __bf16 bf16x4 __attribute__((ext_vector_type(4)));
typedef __bf16 bf16x8 __attribute__((ext_vector_type(8)));
typedef float f32x4 __attribute__((ext_vector_type(4)));

#define MFMA(a, b, c) __builtin_amdgcn_mfma_f32_16x16x32_bf16((a), (b), (c), 0, 0, 0)

// 0.125 * log2(e): folded into Q so scores are already in log2 domain.
#define QSCALE 0.18033688011112042f

// ---------------------------------------------------------------------------
// build_powers: per head h, P = I + (Xi - Xi^T); pows[h][n] = P^(n+1), f32.
// ---------------------------------------------------------------------------
__global__ __launch_bounds__(256) void build_powers(const float* __restrict__ Xi,
                                                    float* __restrict__ pows) {
  const int h = blockIdx.x;
  __shared__ __align__(16) float P[64][68];
  __shared__ __align__(16) float cur[64][68];
  const int tid = threadIdx.x;
  const float* xi = Xi + (size_t)h * 4096;
  float* dst = pows + (size_t)h * 8 * 4096;
  for (int idx = tid; idx < 4096; idx += 256) {
    const int i = idx >> 6, j = idx & 63;
    const float p = (i == j ? 1.f : 0.f) + xi[i * 64 + j] - xi[j * 64 + i];
    P[i][j] = p;
    cur[i][j] = p;
    dst[idx] = p;  // n=0 -> P^1
  }
  __syncthreads();
  const int i = tid >> 2;
  const int j0 = (tid & 3) * 16;
  for (int n = 1; n < 8; ++n) {
    float a[16];
#pragma unroll
    for (int jj = 0; jj < 16; ++jj) a[jj] = 0.f;
    for (int dd = 0; dd < 64; ++dd) {
      const float c = cur[i][dd];
#pragma unroll
      for (int jj = 0; jj < 16; ++jj) a[jj] += c * P[dd][j0 + jj];
    }
    __syncthreads();
#pragma unroll
    for (int jj = 0; jj < 16; ++jj) {
      cur[i][j0 + jj] = a[jj];
      dst[n * 4096 + i * 64 + j0 + jj] = a[jj];
    }
    __syncthreads();
  }
}

// ---------------------------------------------------------------------------
// build_B: Bmat[n][(h*64+d)][e] = sum_dd pows[h][n][d][dd] * Wo[h*64+dd][e]
// grid (4 e-tiles, 8 n, 8 h), bf16 output.
// ---------------------------------------------------------------------------
__global__ __launch_bounds__(256) void build_B(const float* __restrict__ pows,
                                               const float* __restrict__ Wo,
                                               bf16_t* __restrict__ Bmat) {
  const int et = blockIdx.x;
  const int n = blockIdx.y;
  const int h = blockIdx.z;
  __shared__ __align__(16) float P[64][68];
  __shared__ __align__(16) float We[64][128];
  const int tid = threadIdx.x;
  const float* src = pows + ((size_t)h * 8 + n) * 4096;
  for (int idx = tid; idx < 4096; idx += 256) P[idx >> 6][idx & 63] = src[idx];
  const int e0 = et * 128;
  for (int idx = tid; idx < 8192; idx += 256) {
    const int dd = idx >> 7, e = idx & 127;
    We[dd][e] = Wo[(size_t)(h * 64 + dd) * 512 + e0 + e];
  }
  __syncthreads();
  const int d = tid >> 2;
  const int eq = (tid & 3) * 32;
  float acc[32];
#pragma unroll
  for (int j = 0; j < 32; ++j) acc[j] = 0.f;
  for (int dd = 0; dd < 64; ++dd) {
    const float p = P[d][dd];
#pragma unroll
    for (int j = 0; j < 32; ++j) acc[j] += p * We[dd][eq + j];
  }
  bf16_t* dst = Bmat + (size_t)n * 512 * 512 + (size_t)(h * 64 + d) * 512 + e0 + eq;
#pragma unroll
  for (int j = 0; j < 32; ++j) dst[j] = (bf16_t)acc[j];
}

// ---------------------------------------------------------------------------
// qkv_gemm: qkv = X @ Wqkv + bqkv; scatter:
//   q -> qw [b][h][s][64] bf16, PRE-SCALED by 0.125*log2(e)
//   k -> kw [b][h][s][64] bf16
//   v -> vt [b][h][64][s] bf16 (TRANSPOSED, d-major) for direct PV B-fragments
// 128x128 tile, BK=64, 4 waves (2x2), 16x16x32 bf16 MFMA.
// ---------------------------------------------------------------------------
__global__ __launch_bounds__(256) void qkv_gemm(const float* __restrict__ X,
                                                const float* __restrict__ W,
                                                const float* __restrict__ bias,
                                                bf16_t* __restrict__ qw,
                                                bf16_t* __restrict__ kw,
                                                bf16_t* __restrict__ vt) {
  __shared__ __align__(16) bf16_t As[128][72];
  __shared__ __align__(16) bf16_t Bs[128][72];  // transposed: [n][k]
  const int tid = threadIdx.x;
  const int wave = tid >> 6, lane = tid & 63;
  const int g = lane >> 4, li = lane & 15;
  const int row0 = blockIdx.x * 128;
  const int col0 = blockIdx.y * 128;
  const int wm = (wave >> 1) * 64, wn = (wave & 1) * 64;
  f32x4 acc[4][4] = {};
  const int m_st = tid >> 1;
  const int kh = (tid & 1) * 32;
  const int nl = tid & 127;
  const int kq = tid >> 7;
  for (int k0 = 0; k0 < 512; k0 += 64) {
    {
      const float* asrc = X + (size_t)(row0 + m_st) * 512 + k0 + kh;
#pragma unroll
      for (int c = 0; c < 4; ++c) {
        const float4 f0 = ((const float4*)asrc)[c * 2];
        const float4 f1 = ((const float4*)asrc)[c * 2 + 1];
        bf16x8 v;
        v[0] = (bf16_t)f0.x; v[1] = (bf16_t)f0.y; v[2] = (bf16_t)f0.z; v[3] = (bf16_t)f0.w;
        v[4] = (bf16_t)f1.x; v[5] = (bf16_t)f1.y; v[6] = (bf16_t)f1.z; v[7] = (bf16_t)f1.w;
        *(bf16x8*)&As[m_st][kh + c * 8] = v;
      }
      const float* bsrc = W + (size_t)(k0 + kq * 32) * 1536 + col0 + nl;
#pragma unroll
      for (int c = 0; c < 4; ++c) {
        bf16x8 v;
#pragma unroll
        for (int j = 0; j < 8; ++j) v[j] = (bf16_t)bsrc[(size_t)(c * 8 + j) * 1536];
        *(bf16x8*)&Bs[nl][kq * 32 + c * 8] = v;
      }
    }
    __syncthreads();
#pragma unroll
    for (int ks = 0; ks < 2; ++ks) {
      bf16x8 af[4], bfr[4];
#pragma unroll
      for (int mr = 0; mr < 4; ++mr)
        af[mr] = *(const bf16x8*)&As[wm + mr * 16 + li][ks * 32 + g * 8];
#pragma unroll
      for (int nr = 0; nr < 4; ++nr)
        bfr[nr] = *(const bf16x8*)&Bs[wn + nr * 16 + li][ks * 32 + g * 8];
#pragma unroll
      for (int mr = 0; mr < 4; ++mr)
#pragma unroll
        for (int nr = 0; nr < 4; ++nr)
          acc[mr][nr] = MFMA(af[mr], bfr[nr], acc[mr][nr]);
    }
    __syncthreads();
  }
  // epilogue
  const int cbase = col0 + wn;            // multiple of 64
  const int sel = cbase >> 9;             // 0=q 1=k 2=v (uniform per wave)
  const int hh = (cbase & 511) >> 6;      // head (uniform per wave)
  const int bb = row0 >> 11;              // batch (uniform per block)
  const size_t hb = (size_t)(bb * 8 + hh) * (2048 * 64);
  if (sel == 2) {
    // v: transposed store vt[d][s], packed bf16x4 along s
    bf16_t* vbase = vt + hb;
#pragma unroll
    for (int nr = 0; nr < 4; ++nr) {
      const int dcol = nr * 16 + li;
      const float bv = bias[cbase + dcol];
#pragma unroll
      for (int mr = 0; mr < 4; ++mr) {
        bf16x4 pk;
#pragma unroll
        for (int i = 0; i < 4; ++i) pk[i] = (bf16_t)(acc[mr][nr][i] + bv);
        const int s = (row0 + wm + mr * 16 + g * 4) & 2047;
        *(bf16x4*)&vbase[(size_t)dcol * 2048 + s] = pk;
      }
    }
  } else {
    bf16_t* dstp = (sel == 0 ? qw : kw) + hb;
    const float sc = (sel == 0) ? QSCALE : 1.0f;
#pragma unroll
    for (int nr = 0; nr < 4; ++nr) {
      const int dcol = nr * 16 + li;
      const float bv = bias[cbase + dcol];
#pragma unroll
      for (int mr = 0; mr < 4; ++mr) {
#pragma unroll
        for (int i = 0; i < 4; ++i) {
          const int r = row0 + wm + mr * 16 + g * 4 + i;
          const int s = r & 2047;
          dstp[(size_t)s * 64 + dcol] = (bf16_t)((acc[mr][nr][i] + bv) * sc);
        }
      }
    }
  }
}

// ---------------------------------------------------------------------------
// fattn: causal flash attention, barrier-free.
// grid (32 q-tiles reversed, 8 h, 4 b), 4 independent waves x 16 q-rows.
// K fragments read directly from global (L1/L2-resident); V fragments read
// from transposed vt. Only P goes through wave-private LDS (pad 80 -> no
// write conflicts). Scores arrive pre-scaled in log2 domain (exp2f softmax).
// Writes attn_cat [b*2048+s][h*64+d] bf16.
// ---------------------------------------------------------------------------
__global__ __launch_bounds__(256) void fattn(const bf16_t* __restrict__ qw,
                                             const bf16_t* __restrict__ kw,
                                             const bf16_t* __restrict__ vt,
                                             bf16_t* __restrict__ attn) {
  __shared__ __align__(16) bf16_t Ps[4][16][80];
  const int tid = threadIdx.x;
  const int w = tid >> 6;
  const int lane = tid & 63;
  const int g = lane >> 4;
  const int li = lane & 15;
  const int qt = (int)gridDim.x - 1 - (int)blockIdx.x;  // longest blocks first
  const int h = blockIdx.y;
  const int b = blockIdx.z;
  const size_t base = ((size_t)(b * 8 + h)) * (2048 * 64);
  const int q0 = qt * 64;
  const int qrow = q0 + w * 16 + li;
  const bf16x8 aq0 = *(const bf16x8*)(qw + base + (size_t)qrow * 64 + g * 8);
  const bf16x8 aq1 = *(const bf16x8*)(qw + base + (size_t)qrow * 64 + 32 + g * 8);
  const bf16_t* kbase = kw + base;
  const bf16_t* vbase = vt + base;  // [d][2048]
  f32x4 accO[4] = {};
  float m_run[4], l_run[4];
#pragma unroll
  for (int i = 0; i < 4; ++i) {
    m_run[i] = -__builtin_inff();
    l_run[i] = 0.f;
  }
  for (int kt = 0; kt <= qt; ++kt) {
    const int kb = kt * 64;
    // S^ = Q K^T, K fragments direct from global
    f32x4 sv[4];
#pragma unroll
    for (int nt = 0; nt < 4; ++nt) {
      const bf16_t* kp = kbase + (size_t)(kb + nt * 16 + li) * 64 + g * 8;
      const bf16x8 bk0 = *(const bf16x8*)kp;
      const bf16x8 bk1 = *(const bf16x8*)(kp + 32);
      f32x4 z = {0.f, 0.f, 0.f, 0.f};
      z = MFMA(aq0, bk0, z);
      sv[nt] = MFMA(aq1, bk1, z);
    }
    if (kt == qt) {  // only the diagonal tile needs masking
#pragma unroll
      for (int nt = 0; nt < 4; ++nt) {
        const int col = kb + nt * 16 + li;
#pragma unroll
        for (int i = 0; i < 4; ++i) {
          const int row = q0 + w * 16 + g * 4 + i;
          if (col > row) sv[nt][i] = NEGV;
        }
      }
    }
    float pmax[4];
#pragma unroll
    for (int i = 0; i < 4; ++i) pmax[i] = -__builtin_inff();
#pragma unroll
    for (int nt = 0; nt < 4; ++nt)
#pragma unroll
      for (int i = 0; i < 4; ++i) pmax[i] = fmaxf(pmax[i], sv[nt][i]);
#pragma unroll
    for (int off = 1; off < 16; off <<= 1) {
#pragma unroll
      for (int i = 0; i < 4; ++i) pmax[i] = fmaxf(pmax[i], __shfl_xor(pmax[i], off, 64));
    }
    float scale[4], newm[4], rsum[4];
#pragma unroll
    for (int i = 0; i < 4; ++i) {
      newm[i] = fmaxf(m_run[i], pmax[i]);
      scale[i] = exp2f(m_run[i] - newm[i]);
      rsum[i] = 0.f;
    }
#pragma unroll
    for (int nt = 0; nt < 4; ++nt) {
#pragma unroll
      for (int i = 0; i < 4; ++i) {
        const float p = exp2f(sv[nt][i] - newm[i]);
        sv[nt][i] = p;
        rsum[i] += p;
      }
    }
#pragma unroll
    for (int off = 1; off < 16; off <<= 1) {
#pragma unroll
      for (int i = 0; i < 4; ++i) rsum[i] += __shfl_xor(rsum[i], off, 64);
    }
#pragma unroll
    for (int i = 0; i < 4; ++i) {
      l_run[i] = l_run[i] * scale[i] + rsum[i];
      m_run[i] = newm[i];
    }
#pragma unroll
    for (int nt = 0; nt < 4; ++nt)
#pragma unroll
      for (int i = 0; i < 4; ++i) accO[nt][i] *= scale[i];
    // P -> wave-private LDS (cross-lane redistribution for the PV A-operand)
#pragma unroll
    for (int nt = 0; nt < 4; ++nt)
#pragma unroll
      for (int i = 0; i < 4; ++i) Ps[w][g * 4 + i][nt * 16 + li] = (bf16_t)sv[nt][i];
    const bf16x8 ap0 = *(const bf16x8*)&Ps[w][li][g * 8];
    const bf16x8 ap1 = *(const bf16x8*)&Ps[w][li][32 + g * 8];
#pragma unroll
    for (int nt = 0; nt < 4; ++nt) {
      const bf16_t* vp = vbase + (size_t)(nt * 16 + li) * 2048 + kb + g * 8;
      const bf16x8 bv0 = *(const bf16x8*)vp;
      const bf16x8 bv1 = *(const bf16x8*)(vp + 32);
      accO[nt] = MFMA(ap0, bv0, accO[nt]);
      accO[nt] = MFMA(ap1, bv1, accO[nt]);
    }
  }
#pragma unroll
  for (int i = 0; i < 4; ++i) {
    const int row = q0 + w * 16 + g * 4 + i;
    const float inv = 1.0f / l_run[i];
#pragma unroll
    for (int nt = 0; nt < 4; ++nt) {
      attn[(size_t)(b * 2048 + row) * 512 + h * 64 + nt * 16 + li] =
          (bf16_t)(accO[nt][i] * inv);
    }
  }
}

// ---------------------------------------------------------------------------
// out_gemm: out[b][nf][s][:] = attn_cat[b*2048+s][:] @ Bmat[nf] + bo, f32 out.
// grid (64 m-tiles, 4 col-tiles, 8 forecast)
// ---------------------------------------------------------------------------
__global__ __launch_bounds__(256) void out_gemm(const bf16_t* __restrict__ A,
                                                const bf16_t* __restrict__ Bmat,
                                                const float* __restrict__ bo,
                                                float* __restrict__ out) {
  __shared__ __align__(16) bf16_t As[128][72];
  __shared__ __align__(16) bf16_t Bs[128][72];  // transposed: [e][k]
  const int tid = threadIdx.x;
  const int wave = tid >> 6, lane = tid & 63;
  const int g = lane >> 4, li = lane & 15;
  const int row0 = blockIdx.x * 128;
  const int col0 = blockIdx.y * 128;
  const int nf = blockIdx.z;
  const bf16_t* B = Bmat + (size_t)nf * 512 * 512;
  const int wm = (wave >> 1) * 64, wn = (wave & 1) * 64;
  f32x4 acc[4][4] = {};
  const int m_st = tid >> 1;
  const int kh = (tid & 1) * 32;
  const int nl = tid & 127;
  const int kq = tid >> 7;
  for (int k0 = 0; k0 < 512; k0 += 64) {
    {
      const bf16x8* asrc = (const bf16x8*)(A + (size_t)(row0 + m_st) * 512 + k0 + kh);
#pragma unroll
      for (int c = 0; c < 4; ++c) *(bf16x8*)&As[m_st][kh + c * 8] = asrc[c];
      const bf16_t* bsrc = B + (size_t)(k0 + kq * 32) * 512 + col0 + nl;
#pragma unroll
      for (int c = 0; c < 4; ++c) {
        bf16x8 v;
#pragma unroll
        for (int j = 0; j < 8; ++j) v[j] = bsrc[(size_t)(c * 8 + j) * 512];
        *(bf16x8*)&Bs[nl][kq * 32 + c * 8] = v;
      }
    }
    __syncthreads();
#pragma unroll
    for (int ks = 0; ks < 2; ++ks) {
      bf16x8 af[4], bfr[4];
#pragma unroll
      for (int mr = 0; mr < 4; ++mr)
        af[mr] = *(const bf16x8*)&As[wm + mr * 16 + li][ks * 32 + g * 8];
#pragma unroll
      for (int nr = 0; nr < 4; ++nr)
        bfr[nr] = *(const bf16x8*)&Bs[wn + nr * 16 + li][ks * 32 + g * 8];
#pragma unroll
      for (int mr = 0; mr < 4; ++mr)
#pragma unroll
        for (int nr = 0; nr < 4; ++nr)
          acc[mr][nr] = MFMA(af[mr], bfr[nr], acc[mr][nr]);
    }
    __syncthreads();
  }
  const int bb = row0 >> 11;
  float* obase = out + ((size_t)(bb * 8 + nf)) * (2048 * 512);
#pragma unroll
  for (int nr = 0; nr < 4; ++nr) {
    const int c = col0 + wn + nr * 16 + li;
    const float bv = bo[c];
#pragma unroll
    for (int mr = 0; mr < 4; ++mr) {
#pragma unroll
      for (int i = 0; i < 4; ++i) {
        const int r = row0 + wm + mr * 16 + g * 4 + i;
        const int s = r & 2047;
        obase[(size_t)s * 512 + c] = acc[mr][nr][i] + bv;
      }
    }
  }
}

// ---------------------------------------------------------------------------
extern "C" void kernel_launch(void* const* d_in, const int* in_sizes, int n_in,
                              void* d_out, int out_size, void* d_ws, size_t ws_size,
                              hipStream_t stream) {
  const float* query = (const float*)d_in[0];
  // d_in[1]=key, d_in[2]=value are unused by the reference forward.
  const float* Wqkv = (const float*)d_in[3];
  const float* bqkv = (const float*)d_in[4];
  const float* Wo = (const float*)d_in[5];
  const float* bo = (const float*)d_in[6];
  const float* Xi = (const float*)d_in[7];
  float* out = (float*)d_out;

  char* ws = (char*)d_ws;
  bf16_t* qw = (bf16_t*)(ws + 0);                 // [4][8][2048][64] bf16 = 8 MiB (pre-scaled)
  bf16_t* kw = (bf16_t*)(ws + 8388608);           // 8 MiB
  bf16_t* vt = (bf16_t*)(ws + 16777216);          // [4][8][64][2048] bf16 = 8 MiB (transposed)
  bf16_t* attn = (bf16_t*)(ws + 25165824);        // [8192][512] bf16 = 8 MiB
  bf16_t* Bmat = (bf16_t*)(ws + 33554432);        // [8][512][512] bf16 = 4 MiB
  float* pows = (float*)(ws + 37748736);          // [8][8][64][64] f32 = 1 MiB

  build_powers<<<dim3(8), dim3(256), 0, stream>>>(Xi, pows);
  build_B<<<dim3(4, 8, 8), dim3(256), 0, stream>>>(pows, Wo, Bmat);
  qkv_gemm<<<dim3(64, 12), dim3(256), 0, stream>>>(query, Wqkv, bqkv, qw, kw, vt);
  fattn<<<dim3(32, 8, 4), dim3(256), 0, stream>>>(qw, kw, vt, attn);
  out_gemm<<<dim3(64, 4, 8), dim3(256), 0, stream>>>(attn, Bmat, bo, out);
}

// Round 3
// 281.777 us; speedup vs baseline: 1.3550x; 1.3550x over previous
//
#include <hip/hip_runtime.h>
#include <math.h>

// Problem constants: N=4, L=2048, E=512, H=8, hd=64, FORECAST=8
// M = N*L = 8192 token rows.

#define NEGV -1e30f

typedef __bf16 bf16_t;
typedef __bf16 bf16x4 __attribute__((ext_vector_type(4)));
typedef __bf16 bf16x8 __attribute__((ext_vector_type(8)));
typedef float f32x4 __attribute__((ext_vector_type(4)));

#define MFMA(a, b, c) __builtin_amdgcn_mfma_f32_16x16x32_bf16((a), (b), (c), 0, 0, 0)

// 0.125 * log2(e): folded into Q so scores are already in log2 domain.
#define QSCALE 0.18033688011112042f

// ---------------------------------------------------------------------------
// build_powers: per head h, P = I + (Xi - Xi^T); pows[h][n] = P^(n+1), f32.
// ---------------------------------------------------------------------------
__global__ __launch_bounds__(256) void build_powers(const float* __restrict__ Xi,
                                                    float* __restrict__ pows) {
  const int h = blockIdx.x;
  __shared__ __align__(16) float P[64][68];
  __shared__ __align__(16) float cur[64][68];
  const int tid = threadIdx.x;
  const float* xi = Xi + (size_t)h * 4096;
  float* dst = pows + (size_t)h * 8 * 4096;
  for (int idx = tid; idx < 4096; idx += 256) {
    const int i = idx >> 6, j = idx & 63;
    const float p = (i == j ? 1.f : 0.f) + xi[i * 64 + j] - xi[j * 64 + i];
    P[i][j] = p;
    cur[i][j] = p;
    dst[idx] = p;  // n=0 -> P^1
  }
  __syncthreads();
  const int i = tid >> 2;
  const int j0 = (tid & 3) * 16;
  for (int n = 1; n < 8; ++n) {
    float a[16];
#pragma unroll
    for (int jj = 0; jj < 16; ++jj) a[jj] = 0.f;
    for (int dd = 0; dd < 64; ++dd) {
      const float c = cur[i][dd];
#pragma unroll
      for (int jj = 0; jj < 16; ++jj) a[jj] += c * P[dd][j0 + jj];
    }
    __syncthreads();
#pragma unroll
    for (int jj = 0; jj < 16; ++jj) {
      cur[i][j0 + jj] = a[jj];
      dst[n * 4096 + i * 64 + j0 + jj] = a[jj];
    }
    __syncthreads();
  }
}

// ---------------------------------------------------------------------------
// build_B: Bmat[n][(h*64+d)][e] = sum_dd pows[h][n][d][dd] * Wo[h*64+dd][e]
// grid (4 e-tiles, 8 n, 8 h), bf16 output.
// ---------------------------------------------------------------------------
__global__ __launch_bounds__(256) void build_B(const float* __restrict__ pows,
                                               const float* __restrict__ Wo,
                                               bf16_t* __restrict__ Bmat) {
  const int et = blockIdx.x;
  const int n = blockIdx.y;
  const int h = blockIdx.z;
  __shared__ __align__(16) float P[64][68];
  __shared__ __align__(16) float We[64][128];
  const int tid = threadIdx.x;
  const float* src = pows + ((size_t)h * 8 + n) * 4096;
  for (int idx = tid; idx < 4096; idx += 256) P[idx >> 6][idx & 63] = src[idx];
  const int e0 = et * 128;
  for (int idx = tid; idx < 8192; idx += 256) {
    const int dd = idx >> 7, e = idx & 127;
    We[dd][e] = Wo[(size_t)(h * 64 + dd) * 512 + e0 + e];
  }
  __syncthreads();
  const int d = tid >> 2;
  const int eq = (tid & 3) * 32;
  float acc[32];
#pragma unroll
  for (int j = 0; j < 32; ++j) acc[j] = 0.f;
  for (int dd = 0; dd < 64; ++dd) {
    const float p = P[d][dd];
#pragma unroll
    for (int j = 0; j < 32; ++j) acc[j] += p * We[dd][eq + j];
  }
  bf16_t* dst = Bmat + (size_t)n * 512 * 512 + (size_t)(h * 64 + d) * 512 + e0 + eq;
#pragma unroll
  for (int j = 0; j < 32; ++j) dst[j] = (bf16_t)acc[j];
}

// ---------------------------------------------------------------------------
// qkv_gemm: qkv = X @ Wqkv + bqkv; scatter:
//   q -> qw [b][h][s][64] bf16, PRE-SCALED by 0.125*log2(e)
//   k -> kw [b][h][s][64] bf16
//   v -> vt [b][h][64][s] bf16 (TRANSPOSED, d-major)
// ---------------------------------------------------------------------------
__global__ __launch_bounds__(256) void qkv_gemm(const float* __restrict__ X,
                                                const float* __restrict__ W,
                                                const float* __restrict__ bias,
                                                bf16_t* __restrict__ qw,
                                                bf16_t* __restrict__ kw,
                                                bf16_t* __restrict__ vt) {
  __shared__ __align__(16) bf16_t As[128][72];
  __shared__ __align__(16) bf16_t Bs[128][72];  // transposed: [n][k]
  const int tid = threadIdx.x;
  const int wave = tid >> 6, lane = tid & 63;
  const int g = lane >> 4, li = lane & 15;
  const int row0 = blockIdx.x * 128;
  const int col0 = blockIdx.y * 128;
  const int wm = (wave >> 1) * 64, wn = (wave & 1) * 64;
  f32x4 acc[4][4] = {};
  const int m_st = tid >> 1;
  const int kh = (tid & 1) * 32;
  const int nl = tid & 127;
  const int kq = tid >> 7;
  for (int k0 = 0; k0 < 512; k0 += 64) {
    {
      const float* asrc = X + (size_t)(row0 + m_st) * 512 + k0 + kh;
#pragma unroll
      for (int c = 0; c < 4; ++c) {
        const float4 f0 = ((const float4*)asrc)[c * 2];
        const float4 f1 = ((const float4*)asrc)[c * 2 + 1];
        bf16x8 v;
        v[0] = (bf16_t)f0.x; v[1] = (bf16_t)f0.y; v[2] = (bf16_t)f0.z; v[3] = (bf16_t)f0.w;
        v[4] = (bf16_t)f1.x; v[5] = (bf16_t)f1.y; v[6] = (bf16_t)f1.z; v[7] = (bf16_t)f1.w;
        *(bf16x8*)&As[m_st][kh + c * 8] = v;
      }
      const float* bsrc = W + (size_t)(k0 + kq * 32) * 1536 + col0 + nl;
#pragma unroll
      for (int c = 0; c < 4; ++c) {
        bf16x8 v;
#pragma unroll
        for (int j = 0; j < 8; ++j) v[j] = (bf16_t)bsrc[(size_t)(c * 8 + j) * 1536];
        *(bf16x8*)&Bs[nl][kq * 32 + c * 8] = v;
      }
    }
    __syncthreads();
#pragma unroll
    for (int ks = 0; ks < 2; ++ks) {
      bf16x8 af[4], bfr[4];
#pragma unroll
      for (int mr = 0; mr < 4; ++mr)
        af[mr] = *(const bf16x8*)&As[wm + mr * 16 + li][ks * 32 + g * 8];
#pragma unroll
      for (int nr = 0; nr < 4; ++nr)
        bfr[nr] = *(const bf16x8*)&Bs[wn + nr * 16 + li][ks * 32 + g * 8];
#pragma unroll
      for (int mr = 0; mr < 4; ++mr)
#pragma unroll
        for (int nr = 0; nr < 4; ++nr)
          acc[mr][nr] = MFMA(af[mr], bfr[nr], acc[mr][nr]);
    }
    __syncthreads();
  }
  // epilogue
  const int cbase = col0 + wn;            // multiple of 64
  const int sel = cbase >> 9;             // 0=q 1=k 2=v (uniform per wave)
  const int hh = (cbase & 511) >> 6;      // head (uniform per wave)
  const int bb = row0 >> 11;              // batch (uniform per block)
  const size_t hb = (size_t)(bb * 8 + hh) * (2048 * 64);
  if (sel == 2) {
    // v: transposed store vt[d][s], packed bf16x4 along s
    bf16_t* vbase = vt + hb;
#pragma unroll
    for (int nr = 0; nr < 4; ++nr) {
      const int dcol = nr * 16 + li;
      const float bv = bias[cbase + dcol];
#pragma unroll
      for (int mr = 0; mr < 4; ++mr) {
        bf16x4 pk;
#pragma unroll
        for (int i = 0; i < 4; ++i) pk[i] = (bf16_t)(acc[mr][nr][i] + bv);
        const int s = (row0 + wm + mr * 16 + g * 4) & 2047;
        *(bf16x4*)&vbase[(size_t)dcol * 2048 + s] = pk;
      }
    }
  } else {
    bf16_t* dstp = (sel == 0 ? qw : kw) + hb;
    const float sc = (sel == 0) ? QSCALE : 1.0f;
#pragma unroll
    for (int nr = 0; nr < 4; ++nr) {
      const int dcol = nr * 16 + li;
      const float bv = bias[cbase + dcol];
#pragma unroll
      for (int mr = 0; mr < 4; ++mr) {
#pragma unroll
        for (int i = 0; i < 4; ++i) {
          const int r = row0 + wm + mr * 16 + g * 4 + i;
          const int s = r & 2047;
          dstp[(size_t)s * 64 + dcol] = (bf16_t)((acc[mr][nr][i] + bv) * sc);
        }
      }
    }
  }
}

// ---------------------------------------------------------------------------
// fattn: causal flash attention. grid (32 q-tiles reversed, 8 h, 4 b),
// 4 waves x 16 q-rows. Double-buffered LDS staging of K and (pre-transposed)
// V -> ONE barrier per K-tile. T14: next tile's global loads issued before
// the MFMA phase, LDS writes after. T13 defer-max. T5 setprio around MFMA.
// Scores pre-scaled into log2 domain (exp2 softmax).
// ---------------------------------------------------------------------------
__global__ __launch_bounds__(256) void fattn(const bf16_t* __restrict__ qw,
                                             const bf16_t* __restrict__ kw,
                                             const bf16_t* __restrict__ vt,
                                             bf16_t* __restrict__ attn) {
  __shared__ __align__(16) bf16_t Ks[2][64][72];
  __shared__ __align__(16) bf16_t Vs[2][64][72];  // rows = d, cols = key
  __shared__ __align__(16) bf16_t Ps[4][16][88];  // wave-private P tile
  const int tid = threadIdx.x;
  const int w = tid >> 6;
  const int lane = tid & 63;
  const int g = lane >> 4;
  const int li = lane & 15;
  const int qt = (int)gridDim.x - 1 - (int)blockIdx.x;  // longest blocks first
  const int h = blockIdx.y;
  const int b = blockIdx.z;
  const size_t base = ((size_t)(b * 8 + h)) * (2048 * 64);
  const int q0 = qt * 64;
  const int qrow = q0 + w * 16 + li;
  const bf16x8 aq0 = *(const bf16x8*)(qw + base + (size_t)qrow * 64 + g * 8);
  const bf16x8 aq1 = *(const bf16x8*)(qw + base + (size_t)qrow * 64 + 32 + g * 8);
  const bf16_t* kbase = kw + base;
  const bf16_t* vbase = vt + base;  // [64][2048]
  // staging decomposition: thread -> (row r_st, quarter qu), 32B each of K and V
  const int r_st = tid >> 2;  // 0..63
  const int qu = tid & 3;     // 0..3
  // prologue: stage tile 0 into buffer 0
  {
    const bf16_t* kp = kbase + (size_t)r_st * 64 + qu * 16;
    const bf16_t* vp = vbase + (size_t)r_st * 2048 + qu * 16;
    *(bf16x8*)&Ks[0][r_st][qu * 16] = *(const bf16x8*)kp;
    *(bf16x8*)&Ks[0][r_st][qu * 16 + 8] = *(const bf16x8*)(kp + 8);
    *(bf16x8*)&Vs[0][r_st][qu * 16] = *(const bf16x8*)vp;
    *(bf16x8*)&Vs[0][r_st][qu * 16 + 8] = *(const bf16x8*)(vp + 8);
  }
  f32x4 accO[4] = {};
  float m_run[4], l_run[4];
#pragma unroll
  for (int i = 0; i < 4; ++i) {
    m_run[i] = -__builtin_inff();
    l_run[i] = 0.f;
  }
  for (int kt = 0; kt <= qt; ++kt) {
    __syncthreads();  // buf[cur] fully staged; previous compute done
    const int cur = kt & 1;
    const bool pf = kt < qt;
    // T14: issue next tile's global loads now; they land during the MFMA phase
    bf16x8 nk0, nk1, nv0, nv1;
    if (pf) {
      const int kb2 = (kt + 1) * 64;
      const bf16_t* kp = kbase + (size_t)(kb2 + r_st) * 64 + qu * 16;
      const bf16_t* vp = vbase + (size_t)r_st * 2048 + kb2 + qu * 16;
      nk0 = *(const bf16x8*)kp;
      nk1 = *(const bf16x8*)(kp + 8);
      nv0 = *(const bf16x8*)vp;
      nv1 = *(const bf16x8*)(vp + 8);
    }
    // S^ = Q K^T (log2 domain, pre-scaled)
    f32x4 sv[4];
    __builtin_amdgcn_s_setprio(1);
#pragma unroll
    for (int nt = 0; nt < 4; ++nt) {
      const bf16x8 bk0 = *(const bf16x8*)&Ks[cur][nt * 16 + li][g * 8];
      const bf16x8 bk1 = *(const bf16x8*)&Ks[cur][nt * 16 + li][32 + g * 8];
      f32x4 z = {0.f, 0.f, 0.f, 0.f};
      z = MFMA(aq0, bk0, z);
      sv[nt] = MFMA(aq1, bk1, z);
    }
    __builtin_amdgcn_s_setprio(0);
    if (kt == qt) {  // only the diagonal tile needs masking
      const int kb = kt * 64;
#pragma unroll
      for (int nt = 0; nt < 4; ++nt) {
        const int col = kb + nt * 16 + li;
#pragma unroll
        for (int i = 0; i < 4; ++i) {
          const int row = q0 + w * 16 + g * 4 + i;
          if (col > row) sv[nt][i] = NEGV;
        }
      }
    }
    // row max: in-register over nt, shuffle over li
    float pmax[4];
#pragma unroll
    for (int i = 0; i < 4; ++i)
      pmax[i] = fmaxf(fmaxf(sv[0][i], sv[1][i]), fmaxf(sv[2][i], sv[3][i]));
#pragma unroll
    for (int off = 1; off < 16; off <<= 1) {
#pragma unroll
      for (int i = 0; i < 4; ++i) pmax[i] = fmaxf(pmax[i], __shfl_xor(pmax[i], off, 64));
    }
    // T13 defer-max: only rescale when max grew by > 8 (log2 domain)
    float need = pmax[0] - m_run[0];
#pragma unroll
    for (int i = 1; i < 4; ++i) need = fmaxf(need, pmax[i] - m_run[i]);
    if (!__all(need <= 8.f)) {
#pragma unroll
      for (int i = 0; i < 4; ++i) {
        const float newm = fmaxf(m_run[i], pmax[i]);
        const float sc = exp2f(m_run[i] - newm);
        l_run[i] *= sc;
        m_run[i] = newm;
#pragma unroll
        for (int nt = 0; nt < 4; ++nt) accO[nt][i] *= sc;
      }
    }
    // P = exp2(S - m), row sums
    float rsum[4] = {0.f, 0.f, 0.f, 0.f};
#pragma unroll
    for (int nt = 0; nt < 4; ++nt) {
#pragma unroll
      for (int i = 0; i < 4; ++i) {
        const float p = exp2f(sv[nt][i] - m_run[i]);
        sv[nt][i] = p;
        rsum[i] += p;
      }
    }
#pragma unroll
    for (int off = 1; off < 16; off <<= 1) {
#pragma unroll
      for (int i = 0; i < 4; ++i) rsum[i] += __shfl_xor(rsum[i], off, 64);
    }
#pragma unroll
    for (int i = 0; i < 4; ++i) l_run[i] += rsum[i];
    // P -> wave-private LDS (cross-lane redistribution for PV A-operand)
#pragma unroll
    for (int nt = 0; nt < 4; ++nt)
#pragma unroll
      for (int i = 0; i < 4; ++i) Ps[w][g * 4 + i][nt * 16 + li] = (bf16_t)sv[nt][i];
    const bf16x8 ap0 = *(const bf16x8*)&Ps[w][li][g * 8];
    const bf16x8 ap1 = *(const bf16x8*)&Ps[w][li][32 + g * 8];
    __builtin_amdgcn_s_setprio(1);
#pragma unroll
    for (int nt = 0; nt < 4; ++nt) {
      const bf16x8 bv0 = *(const bf16x8*)&Vs[cur][nt * 16 + li][g * 8];
      const bf16x8 bv1 = *(const bf16x8*)&Vs[cur][nt * 16 + li][32 + g * 8];
      accO[nt] = MFMA(ap0, bv0, accO[nt]);
      accO[nt] = MFMA(ap1, bv1, accO[nt]);
    }
    __builtin_amdgcn_s_setprio(0);
    // write next tile's staged regs into the other buffer (before next barrier)
    if (pf) {
      *(bf16x8*)&Ks[cur ^ 1][r_st][qu * 16] = nk0;
      *(bf16x8*)&Ks[cur ^ 1][r_st][qu * 16 + 8] = nk1;
      *(bf16x8*)&Vs[cur ^ 1][r_st][qu * 16] = nv0;
      *(bf16x8*)&Vs[cur ^ 1][r_st][qu * 16 + 8] = nv1;
    }
  }
#pragma unroll
  for (int i = 0; i < 4; ++i) {
    const int row = q0 + w * 16 + g * 4 + i;
    const float inv = 1.0f / l_run[i];
#pragma unroll
    for (int nt = 0; nt < 4; ++nt) {
      attn[(size_t)(b * 2048 + row) * 512 + h * 64 + nt * 16 + li] =
          (bf16_t)(accO[nt][i] * inv);
    }
  }
}

// ---------------------------------------------------------------------------
// out_gemm: out[b][nf][s][:] = attn_cat[b*2048+s][:] @ Bmat[nf] + bo, f32 out.
// grid (64 m-tiles, 4 col-tiles, 8 forecast)
// ---------------------------------------------------------------------------
__global__ __launch_bounds__(256) void out_gemm(const bf16_t* __restrict__ A,
                                                const bf16_t* __restrict__ Bmat,
                                                const float* __restrict__ bo,
                                                float* __restrict__ out) {
  __shared__ __align__(16) bf16_t As[128][72];
  __shared__ __align__(16) bf16_t Bs[128][72];  // transposed: [e][k]
  const int tid = threadIdx.x;
  const int wave = tid >> 6, lane = tid & 63;
  const int g = lane >> 4, li = lane & 15;
  const int row0 = blockIdx.x * 128;
  const int col0 = blockIdx.y * 128;
  const int nf = blockIdx.z;
  const bf16_t* B = Bmat + (size_t)nf * 512 * 512;
  const int wm = (wave >> 1) * 64, wn = (wave & 1) * 64;
  f32x4 acc[4][4] = {};
  const int m_st = tid >> 1;
  const int kh = (tid & 1) * 32;
  const int nl = tid & 127;
  const int kq = tid >> 7;
  for (int k0 = 0; k0 < 512; k0 += 64) {
    {
      const bf16x8* asrc = (const bf16x8*)(A + (size_t)(row0 + m_st) * 512 + k0 + kh);
#pragma unroll
      for (int c = 0; c < 4; ++c) *(bf16x8*)&As[m_st][kh + c * 8] = asrc[c];
      const bf16_t* bsrc = B + (size_t)(k0 + kq * 32) * 512 + col0 + nl;
#pragma unroll
      for (int c = 0; c < 4; ++c) {
        bf16x8 v;
#pragma unroll
        for (int j = 0; j < 8; ++j) v[j] = bsrc[(size_t)(c * 8 + j) * 512];
        *(bf16x8*)&Bs[nl][kq * 32 + c * 8] = v;
      }
    }
    __syncthreads();
#pragma unroll
    for (int ks = 0; ks < 2; ++ks) {
      bf16x8 af[4], bfr[4];
#pragma unroll
      for (int mr = 0; mr < 4; ++mr)
        af[mr] = *(const bf16x8*)&As[wm + mr * 16 + li][ks * 32 + g * 8];
#pragma unroll
      for (int nr = 0; nr < 4; ++nr)
        bfr[nr] = *(const bf16x8*)&Bs[wn + nr * 16 + li][ks * 32 + g * 8];
#pragma unroll
      for (int mr = 0; mr < 4; ++mr)
#pragma unroll
        for (int nr = 0; nr < 4; ++nr)
          acc[mr][nr] = MFMA(af[mr], bfr[nr], acc[mr][nr]);
    }
    __syncthreads();
  }
  const int bb = row0 >> 11;
  float* obase = out + ((size_t)(bb * 8 + nf)) * (2048 * 512);
#pragma unroll
  for (int nr = 0; nr < 4; ++nr) {
    const int c = col0 + wn + nr * 16 + li;
    const float bv = bo[c];
#pragma unroll
    for (int mr = 0; mr < 4; ++mr) {
#pragma unroll
      for (int i = 0; i < 4; ++i) {
        const int r = row0 + wm + mr * 16 + g * 4 + i;
        const int s = r & 2047;
        obase[(size_t)s * 512 + c] = acc[mr][nr][i] + bv;
      }
    }
  }
}

// ---------------------------------------------------------------------------
extern "C" void kernel_launch(void* const* d_in, const int* in_sizes, int n_in,
                              void* d_out, int out_size, void* d_ws, size_t ws_size,
                              hipStream_t stream) {
  const float* query = (const float*)d_in[0];
  // d_in[1]=key, d_in[2]=value are unused by the reference forward.
  const float* Wqkv = (const float*)d_in[3];
  const float* bqkv = (const float*)d_in[4];
  const float* Wo = (const float*)d_in[5];
  const float* bo = (const float*)d_in[6];
  const float* Xi = (const float*)d_in[7];
  float* out = (float*)d_out;

  char* ws = (char*)d_ws;
  bf16_t* qw = (bf16_t*)(ws + 0);                 // [4][8][2048][64] bf16 = 8 MiB (pre-scaled)
  bf16_t* kw = (bf16_t*)(ws + 8388608);           // 8 MiB
  bf16_t* vt = (bf16_t*)(ws + 16777216);          // [4][8][64][2048] bf16 = 8 MiB (transposed)
  bf16_t* attn = (bf16_t*)(ws + 25165824);        // [8192][512] bf16 = 8 MiB
  bf16_t* Bmat = (bf16_t*)(ws + 33554432);        // [8][512][512] bf16 = 4 MiB
  float* pows = (float*)(ws + 37748736);          // [8][8][64][64] f32 = 1 MiB

  build_powers<<<dim3(8), dim3(256), 0, stream>>>(Xi, pows);
  build_B<<<dim3(4, 8, 8), dim3(256), 0, stream>>>(pows, Wo, Bmat);
  qkv_gemm<<<dim3(64, 12), dim3(256), 0, stream>>>(query, Wqkv, bqkv, qw, kw, vt);
  fattn<<<dim3(32, 8, 4), dim3(256), 0, stream>>>(qw, kw, vt, attn);
  out_gemm<<<dim3(64, 4, 8), dim3(256), 0, stream>>>(attn, Bmat, bo, out);
}

// Round 5
// 219.238 us; speedup vs baseline: 1.7415x; 1.2853x over previous
//
#include <hip/hip_runtime.h>
#include <math.h>

// Problem constants: N=4, L=2048, E=512, H=8, hd=64, FORECAST=8
// M = N*L = 8192 token rows.

#define NEGV -1e30f

typedef __bf16 bf16_t;
typedef __bf16 bf16x4 __attribute__((ext_vector_type(4)));
typedef __bf16 bf16x8 __attribute__((ext_vector_type(8)));
typedef float f32x4 __attribute__((ext_vector_type(4)));

#define MFMA(a, b, c) __builtin_amdgcn_mfma_f32_16x16x32_bf16((a), (b), (c), 0, 0, 0)

// 0.125 * log2(e): folded into Q so scores are already in log2 domain.
#define QSCALE 0.18033688011112042f

// Swizzled LDS access for [64][64]-bf16 tiles (row stride 128 B):
// byte = r*128 + (colbyte ^ ((r&7)<<4)).  Applied on BOTH write and read.
__device__ __forceinline__ bf16x8* swz_ptr(bf16_t* base, int r, int cb) {
  return (bf16x8*)((char*)base + r * 128 + (cb ^ ((r & 7) << 4)));
}
__device__ __forceinline__ const bf16x8* swz_cptr(const bf16_t* base, int r, int cb) {
  return (const bf16x8*)((const char*)base + r * 128 + (cb ^ ((r & 7) << 4)));
}

// ---------------------------------------------------------------------------
// build_powers: per head h, P = I + (Xi - Xi^T); pows[h][n] = P^(n+1), f32.
// ---------------------------------------------------------------------------
__global__ __launch_bounds__(256) void build_powers(const float* __restrict__ Xi,
                                                    float* __restrict__ pows) {
  const int h = blockIdx.x;
  __shared__ __align__(16) float P[64][68];
  __shared__ __align__(16) float cur[64][68];
  const int tid = threadIdx.x;
  const float* xi = Xi + (size_t)h * 4096;
  float* dst = pows + (size_t)h * 8 * 4096;
  for (int idx = tid; idx < 4096; idx += 256) {
    const int i = idx >> 6, j = idx & 63;
    const float p = (i == j ? 1.f : 0.f) + xi[i * 64 + j] - xi[j * 64 + i];
    P[i][j] = p;
    cur[i][j] = p;
    dst[idx] = p;  // n=0 -> P^1
  }
  __syncthreads();
  const int i = tid >> 2;
  const int j0 = (tid & 3) * 16;
  for (int n = 1; n < 8; ++n) {
    float a[16];
#pragma unroll
    for (int jj = 0; jj < 16; ++jj) a[jj] = 0.f;
    for (int dd = 0; dd < 64; ++dd) {
      const float c = cur[i][dd];
#pragma unroll
      for (int jj = 0; jj < 16; ++jj) a[jj] += c * P[dd][j0 + jj];
    }
    __syncthreads();
#pragma unroll
    for (int jj = 0; jj < 16; ++jj) {
      cur[i][j0 + jj] = a[jj];
      dst[n * 4096 + i * 64 + j0 + jj] = a[jj];
    }
    __syncthreads();
  }
}

// ---------------------------------------------------------------------------
// build_B: BmatT[n][e][(h*64+d)] = sum_dd pows[h][n][d][dd] * Wo[h*64+dd][e]
// (TRANSPOSED output so out_gemm can stage B with vector loads.)
// grid (4 e-tiles, 8 n, 8 h), bf16 output.
// ---------------------------------------------------------------------------
__global__ __launch_bounds__(256) void build_B(const float* __restrict__ pows,
                                               const float* __restrict__ Wo,
                                               bf16_t* __restrict__ BmatT) {
  const int et = blockIdx.x;
  const int n = blockIdx.y;
  const int h = blockIdx.z;
  __shared__ __align__(16) float P[64][68];
  __shared__ __align__(16) float We[64][128];
  const int tid = threadIdx.x;
  const float* src = pows + ((size_t)h * 8 + n) * 4096;
  for (int idx = tid; idx < 4096; idx += 256) P[idx >> 6][idx & 63] = src[idx];
  const int e0 = et * 128;
  for (int idx = tid; idx < 8192; idx += 256) {
    const int dd = idx >> 7, e = idx & 127;
    We[dd][e] = Wo[(size_t)(h * 64 + dd) * 512 + e0 + e];
  }
  __syncthreads();
  const int d = tid >> 2;
  const int eq = (tid & 3) * 32;
  float acc[32];
#pragma unroll
  for (int j = 0; j < 32; ++j) acc[j] = 0.f;
  for (int dd = 0; dd < 64; ++dd) {
    const float p = P[d][dd];
#pragma unroll
    for (int j = 0; j < 32; ++j) acc[j] += p * We[dd][eq + j];
  }
  // transposed scatter: BmatT[n][e0+eq+j][h*64+d]
  bf16_t* dst = BmatT + (size_t)n * 512 * 512 + (size_t)(e0 + eq) * 512 + h * 64 + d;
#pragma unroll
  for (int j = 0; j < 32; ++j) dst[(size_t)j * 512] = (bf16_t)acc[j];
}

// ---------------------------------------------------------------------------
// qkv_gemm: qkv = X @ Wqkv + bqkv; scatter:
//   q -> qw [b][h][s][64] bf16, PRE-SCALED by 0.125*log2(e)
//   k -> kw [b][h][s][64] bf16
//   v -> vt [b][h][64][s] bf16 (TRANSPOSED, d-major)
// ---------------------------------------------------------------------------
__global__ __launch_bounds__(256) void qkv_gemm(const float* __restrict__ X,
                                                const float* __restrict__ W,
                                                const float* __restrict__ bias,
                                                bf16_t* __restrict__ qw,
                                                bf16_t* __restrict__ kw,
                                                bf16_t* __restrict__ vt) {
  __shared__ __align__(16) bf16_t As[128][72];
  __shared__ __align__(16) bf16_t Bs[128][72];  // transposed: [n][k]
  const int tid = threadIdx.x;
  const int wave = tid >> 6, lane = tid & 63;
  const int g = lane >> 4, li = lane & 15;
  const int row0 = blockIdx.x * 128;
  const int col0 = blockIdx.y * 128;
  const int wm = (wave >> 1) * 64, wn = (wave & 1) * 64;
  f32x4 acc[4][4] = {};
  const int m_st = tid >> 1;
  const int kh = (tid & 1) * 32;
  const int nl = tid & 127;
  const int kq = tid >> 7;
  for (int k0 = 0; k0 < 512; k0 += 64) {
    {
      const float* asrc = X + (size_t)(row0 + m_st) * 512 + k0 + kh;
#pragma unroll
      for (int c = 0; c < 4; ++c) {
        const float4 f0 = ((const float4*)asrc)[c * 2];
        const float4 f1 = ((const float4*)asrc)[c * 2 + 1];
        bf16x8 v;
        v[0] = (bf16_t)f0.x; v[1] = (bf16_t)f0.y; v[2] = (bf16_t)f0.z; v[3] = (bf16_t)f0.w;
        v[4] = (bf16_t)f1.x; v[5] = (bf16_t)f1.y; v[6] = (bf16_t)f1.z; v[7] = (bf16_t)f1.w;
        *(bf16x8*)&As[m_st][kh + c * 8] = v;
      }
      const float* bsrc = W + (size_t)(k0 + kq * 32) * 1536 + col0 + nl;
#pragma unroll
      for (int c = 0; c < 4; ++c) {
        bf16x8 v;
#pragma unroll
        for (int j = 0; j < 8; ++j) v[j] = (bf16_t)bsrc[(size_t)(c * 8 + j) * 1536];
        *(bf16x8*)&Bs[nl][kq * 32 + c * 8] = v;
      }
    }
    __syncthreads();
#pragma unroll
    for (int ks = 0; ks < 2; ++ks) {
      bf16x8 af[4], bfr[4];
#pragma unroll
      for (int mr = 0; mr < 4; ++mr)
        af[mr] = *(const bf16x8*)&As[wm + mr * 16 + li][ks * 32 + g * 8];
#pragma unroll
      for (int nr = 0; nr < 4; ++nr)
        bfr[nr] = *(const bf16x8*)&Bs[wn + nr * 16 + li][ks * 32 + g * 8];
#pragma unroll
      for (int mr = 0; mr < 4; ++mr)
#pragma unroll
        for (int nr = 0; nr < 4; ++nr)
          acc[mr][nr] = MFMA(af[mr], bfr[nr], acc[mr][nr]);
    }
    __syncthreads();
  }
  // epilogue
  const int cbase = col0 + wn;            // multiple of 64
  const int sel = cbase >> 9;             // 0=q 1=k 2=v (uniform per wave)
  const int hh = (cbase & 511) >> 6;      // head (uniform per wave)
  const int bb = row0 >> 11;              // batch (uniform per block)
  const size_t hb = (size_t)(bb * 8 + hh) * (2048 * 64);
  if (sel == 2) {
    // v: transposed store vt[d][s], packed bf16x4 along s
    bf16_t* vbase = vt + hb;
#pragma unroll
    for (int nr = 0; nr < 4; ++nr) {
      const int dcol = nr * 16 + li;
      const float bv = bias[cbase + dcol];
#pragma unroll
      for (int mr = 0; mr < 4; ++mr) {
        bf16x4 pk;
#pragma unroll
        for (int i = 0; i < 4; ++i) pk[i] = (bf16_t)(acc[mr][nr][i] + bv);
        const int s = (row0 + wm + mr * 16 + g * 4) & 2047;
        *(bf16x4*)&vbase[(size_t)dcol * 2048 + s] = pk;
      }
    }
  } else {
    bf16_t* dstp = (sel == 0 ? qw : kw) + hb;
    const float sc = (sel == 0) ? QSCALE : 1.0f;
#pragma unroll
    for (int nr = 0; nr < 4; ++nr) {
      const int dcol = nr * 16 + li;
      const float bv = bias[cbase + dcol];
#pragma unroll
      for (int mr = 0; mr < 4; ++mr) {
#pragma unroll
        for (int i = 0; i < 4; ++i) {
          const int r = row0 + wm + mr * 16 + g * 4 + i;
          const int s = r & 2047;
          dstp[(size_t)s * 64 + dcol] = (bf16_t)((acc[mr][nr][i] + bv) * sc);
        }
      }
    }
  }
}

// ---------------------------------------------------------------------------
// fattn: causal flash attention, SWAPPED-OPERAND layout.
// grid (32 q-tiles reversed, 8 h, 4 b), 4 waves x 16 q-rows.
//   S^T = MFMA(K_frag, Q_frag): lane holds 16 scores of ONE q-row (q = li,
//     keys nt*16 + g*4 + i) -> scalar m/l state, in-lane max/sum + 2 shuffles.
//   O^T = MFMA(V^T_frag, P^T_frag): output rows are q = li again -> no
//     cross-lane fix-ups for rescale or epilogue.
// K/V double-buffered in XOR-swizzled LDS (T2), ONE barrier per tile,
// T14 async staging, T13 defer-max, T5 setprio.
// Ps = [4][16][64] UNPADDED (keys 0..63 per q-row!) with the same XOR
// swizzle keyed on (li&7) -> LDS total 40960 B = exactly 4 blocks/CU.
// ---------------------------------------------------------------------------
__global__ __launch_bounds__(256, 4) void fattn(const bf16_t* __restrict__ qw,
                                                const bf16_t* __restrict__ kw,
                                                const bf16_t* __restrict__ vt,
                                                bf16_t* __restrict__ attn) {
  __shared__ __align__(16) bf16_t Ks[2][64][64];
  __shared__ __align__(16) bf16_t Vs[2][64][64];  // rows = d, cols = key
  __shared__ __align__(16) bf16_t Ps[4][16][64];  // wave-private P^T source, swizzled
  const int tid = threadIdx.x;
  const int w = tid >> 6;
  const int lane = tid & 63;
  const int g = lane >> 4;
  const int li = lane & 15;
  const int qt = (int)gridDim.x - 1 - (int)blockIdx.x;  // longest blocks first
  const int h = blockIdx.y;
  const int b = blockIdx.z;
  const size_t base = ((size_t)(b * 8 + h)) * (2048 * 64);
  const int q0 = qt * 64;
  const int qrow = q0 + w * 16 + li;  // this lane's q-row
  const bf16x8 aq0 = *(const bf16x8*)(qw + base + (size_t)qrow * 64 + g * 8);
  const bf16x8 aq1 = *(const bf16x8*)(qw + base + (size_t)qrow * 64 + 32 + g * 8);
  const bf16_t* kbase = kw + base;
  const bf16_t* vbase = vt + base;  // [64][2048]
  const int r_st = tid >> 2;  // staging row 0..63
  const int qu = tid & 3;     // staging quarter
  // prologue: stage tile 0 into buffer 0 (swizzled)
  {
    const bf16_t* kp = kbase + (size_t)r_st * 64 + qu * 16;
    const bf16_t* vp = vbase + (size_t)r_st * 2048 + qu * 16;
    *swz_ptr(&Ks[0][0][0], r_st, qu * 32) = *(const bf16x8*)kp;
    *swz_ptr(&Ks[0][0][0], r_st, qu * 32 + 16) = *(const bf16x8*)(kp + 8);
    *swz_ptr(&Vs[0][0][0], r_st, qu * 32) = *(const bf16x8*)vp;
    *swz_ptr(&Vs[0][0][0], r_st, qu * 32 + 16) = *(const bf16x8*)(vp + 8);
  }
  f32x4 accO[4] = {};  // accO[nt][i] = O^T: q=li, d = nt*16 + g*4 + i
  float m_run = -__builtin_inff();
  float l_run = 0.f;
  // P-row LDS addressing (wave-private, swizzled by (li&7))
  char* const psrow = (char*)&Ps[w][li][0];
  const int pswz = (li & 7) << 4;
  for (int kt = 0; kt <= qt; ++kt) {
    __syncthreads();  // buf[cur] fully staged; previous compute done
    const int cur = kt & 1;
    const bool pf = kt < qt;
    // T14: issue next tile's global loads now; they land during the MFMA phase
    bf16x8 nk0, nk1, nv0, nv1;
    if (pf) {
      const int kb2 = (kt + 1) * 64;
      const bf16_t* kp = kbase + (size_t)(kb2 + r_st) * 64 + qu * 16;
      const bf16_t* vp = vbase + (size_t)r_st * 2048 + kb2 + qu * 16;
      nk0 = *(const bf16x8*)kp;
      nk1 = *(const bf16x8*)(kp + 8);
      nv0 = *(const bf16x8*)vp;
      nv1 = *(const bf16x8*)(vp + 8);
    }
    // S^T tile: sv[nt][i] = S[q = li][key = kb + nt*16 + g*4 + i]
    f32x4 sv[4];
    __builtin_amdgcn_s_setprio(1);
#pragma unroll
    for (int nt = 0; nt < 4; ++nt) {
      const bf16x8 bk0 = *swz_cptr(&Ks[cur][0][0], nt * 16 + li, g * 16);
      const bf16x8 bk1 = *swz_cptr(&Ks[cur][0][0], nt * 16 + li, 64 + g * 16);
      f32x4 z = {0.f, 0.f, 0.f, 0.f};
      z = MFMA(bk0, aq0, z);
      sv[nt] = MFMA(bk1, aq1, z);
    }
    __builtin_amdgcn_s_setprio(0);
    if (kt == qt) {  // diagonal tile mask: key > q-row
#pragma unroll
      for (int nt = 0; nt < 4; ++nt)
#pragma unroll
        for (int i = 0; i < 4; ++i)
          if (nt * 16 + g * 4 + i > w * 16 + li) sv[nt][i] = NEGV;
    }
    // row max: 15 in-lane + 2 shuffles (row lives in lanes li, li^16, li^32, li^48)
    float pmax = sv[0][0];
#pragma unroll
    for (int nt = 0; nt < 4; ++nt)
#pragma unroll
      for (int i = 0; i < 4; ++i) pmax = fmaxf(pmax, sv[nt][i]);
    pmax = fmaxf(pmax, __shfl_xor(pmax, 16, 64));
    pmax = fmaxf(pmax, __shfl_xor(pmax, 32, 64));
    // T13 defer-max: only rescale when max grew by > 8 (log2 domain)
    if (!__all(pmax - m_run <= 8.f)) {
      const float newm = fmaxf(m_run, pmax);
      const float sc = exp2f(m_run - newm);
      l_run *= sc;
      m_run = newm;
#pragma unroll
      for (int nt = 0; nt < 4; ++nt)
#pragma unroll
        for (int i = 0; i < 4; ++i) accO[nt][i] *= sc;
    }
    // P = exp2(S - m), in-lane sum + 2 shuffles
    float rsum = 0.f;
#pragma unroll
    for (int nt = 0; nt < 4; ++nt) {
#pragma unroll
      for (int i = 0; i < 4; ++i) {
        const float p = exp2f(sv[nt][i] - m_run);
        sv[nt][i] = p;
        rsum += p;
      }
    }
    rsum += __shfl_xor(rsum, 16, 64);
    rsum += __shfl_xor(rsum, 32, 64);
    l_run += rsum;
    // P -> wave-private LDS, packed bf16x4, XOR-swizzled (4 x ds_write_b64)
#pragma unroll
    for (int nt = 0; nt < 4; ++nt) {
      bf16x4 pk;
#pragma unroll
      for (int i = 0; i < 4; ++i) pk[i] = (bf16_t)sv[nt][i];
      *(bf16x4*)(psrow + ((nt * 32 + g * 8) ^ pswz)) = pk;
    }
    const bf16x8 ap0 = *(const bf16x8*)(psrow + ((g * 16) ^ pswz));
    const bf16x8 ap1 = *(const bf16x8*)(psrow + ((64 + g * 16) ^ pswz));
    // O^T += V^T * P^T
    __builtin_amdgcn_s_setprio(1);
#pragma unroll
    for (int nt = 0; nt < 4; ++nt) {
      const bf16x8 bv0 = *swz_cptr(&Vs[cur][0][0], nt * 16 + li, g * 16);
      const bf16x8 bv1 = *swz_cptr(&Vs[cur][0][0], nt * 16 + li, 64 + g * 16);
      accO[nt] = MFMA(bv0, ap0, accO[nt]);
      accO[nt] = MFMA(bv1, ap1, accO[nt]);
    }
    __builtin_amdgcn_s_setprio(0);
    // write next tile's staged regs into the other buffer (before next barrier)
    if (pf) {
      *swz_ptr(&Ks[cur ^ 1][0][0], r_st, qu * 32) = nk0;
      *swz_ptr(&Ks[cur ^ 1][0][0], r_st, qu * 32 + 16) = nk1;
      *swz_ptr(&Vs[cur ^ 1][0][0], r_st, qu * 32) = nv0;
      *swz_ptr(&Vs[cur ^ 1][0][0], r_st, qu * 32 + 16) = nv1;
    }
  }
  // epilogue: lane owns q-row = qrow, d = nt*16 + g*4 .. +3 (packed 8B stores)
  {
    const float inv = 1.0f / l_run;
    bf16_t* arow = attn + (size_t)(b * 2048 + qrow) * 512 + h * 64;
#pragma unroll
    for (int nt = 0; nt < 4; ++nt) {
      bf16x4 pk;
#pragma unroll
      for (int i = 0; i < 4; ++i) pk[i] = (bf16_t)(accO[nt][i] * inv);
      *(bf16x4*)&arow[nt * 16 + g * 4] = pk;
    }
  }
}

// ---------------------------------------------------------------------------
// out_gemm: out[b][nf][s][:] = attn_cat[b*2048+s][:] @ B[nf] + bo, f32 out.
// B supplied TRANSPOSED (BmatT[nf][e][k]) -> vectorized staging.
// grid (64 m-tiles, 4 col-tiles, 8 forecast)
// ---------------------------------------------------------------------------
__global__ __launch_bounds__(256) void out_gemm(const bf16_t* __restrict__ A,
                                                const bf16_t* __restrict__ BmatT,
                                                const float* __restrict__ bo,
                                                float* __restrict__ out) {
  __shared__ __align__(16) bf16_t As[128][72];
  __shared__ __align__(16) bf16_t Bs[128][72];  // [e][k]
  const int tid = threadIdx.x;
  const int wave = tid >> 6, lane = tid & 63;
  const int g = lane >> 4, li = lane & 15;
  const int row0 = blockIdx.x * 128;
  const int col0 = blockIdx.y * 128;
  const int nf = blockIdx.z;
  const bf16_t* BT = BmatT + (size_t)nf * 512 * 512;
  const int wm = (wave >> 1) * 64, wn = (wave & 1) * 64;
  f32x4 acc[4][4] = {};
  const int m_st = tid >> 1;
  const int kh = (tid & 1) * 32;
  for (int k0 = 0; k0 < 512; k0 += 64) {
    {
      const bf16x8* asrc = (const bf16x8*)(A + (size_t)(row0 + m_st) * 512 + k0 + kh);
#pragma unroll
      for (int c = 0; c < 4; ++c) *(bf16x8*)&As[m_st][kh + c * 8] = asrc[c];
      const bf16x8* bsrc = (const bf16x8*)(BT + (size_t)(col0 + m_st) * 512 + k0 + kh);
#pragma unroll
      for (int c = 0; c < 4; ++c) *(bf16x8*)&Bs[m_st][kh + c * 8] = bsrc[c];
    }
    __syncthreads();
#pragma unroll
    for (int ks = 0; ks < 2; ++ks) {
      bf16x8 af[4], bfr[4];
#pragma unroll
      for (int mr = 0; mr < 4; ++mr)
        af[mr] = *(const bf16x8*)&As[wm + mr * 16 + li][ks * 32 + g * 8];
#pragma unroll
      for (int nr = 0; nr < 4; ++nr)
        bfr[nr] = *(const bf16x8*)&Bs[wn + nr * 16 + li][ks * 32 + g * 8];
#pragma unroll
      for (int mr = 0; mr < 4; ++mr)
#pragma unroll
        for (int nr = 0; nr < 4; ++nr)
          acc[mr][nr] = MFMA(af[mr], bfr[nr], acc[mr][nr]);
    }
    __syncthreads();
  }
  const int bb = row0 >> 11;
  float* obase = out + ((size_t)(bb * 8 + nf)) * (2048 * 512);
#pragma unroll
  for (int nr = 0; nr < 4; ++nr) {
    const int c = col0 + wn + nr * 16 + li;
    const float bv = bo[c];
#pragma unroll
    for (int mr = 0; mr < 4; ++mr) {
#pragma unroll
      for (int i = 0; i < 4; ++i) {
        const int r = row0 + wm + mr * 16 + g * 4 + i;
        const int s = r & 2047;
        obase[(size_t)s * 512 + c] = acc[mr][nr][i] + bv;
      }
    }
  }
}

// ---------------------------------------------------------------------------
extern "C" void kernel_launch(void* const* d_in, const int* in_sizes, int n_in,
                              void* d_out, int out_size, void* d_ws, size_t ws_size,
                              hipStream_t stream) {
  const float* query = (const float*)d_in[0];
  // d_in[1]=key, d_in[2]=value are unused by the reference forward.
  const float* Wqkv = (const float*)d_in[3];
  const float* bqkv = (const float*)d_in[4];
  const float* Wo = (const float*)d_in[5];
  const float* bo = (const float*)d_in[6];
  const float* Xi = (const float*)d_in[7];
  float* out = (float*)d_out;

  char* ws = (char*)d_ws;
  bf16_t* qw = (bf16_t*)(ws + 0);                 // [4][8][2048][64] bf16 = 8 MiB (pre-scaled)
  bf16_t* kw = (bf16_t*)(ws + 8388608);           // 8 MiB
  bf16_t* vt = (bf16_t*)(ws + 16777216);          // [4][8][64][2048] bf16 = 8 MiB (transposed)
  bf16_t* attn = (bf16_t*)(ws + 25165824);        // [8192][512] bf16 = 8 MiB
  bf16_t* BmatT = (bf16_t*)(ws + 33554432);       // [8][512][512] bf16 = 4 MiB (transposed)
  float* pows = (float*)(ws + 37748736);          // [8][8][64][64] f32 = 1 MiB

  build_powers<<<dim3(8), dim3(256), 0, stream>>>(Xi, pows);
  build_B<<<dim3(4, 8, 8), dim3(256), 0, stream>>>(pows, Wo, BmatT);
  qkv_gemm<<<dim3(64, 12), dim3(256), 0, stream>>>(query, Wqkv, bqkv, qw, kw, vt);
  fattn<<<dim3(32, 8, 4), dim3(256), 0, stream>>>(qw, kw, vt, attn);
  out_gemm<<<dim3(64, 4, 8), dim3(256), 0, stream>>>(attn, BmatT, bo, out);
}

// Round 6
// 189.962 us; speedup vs baseline: 2.0099x; 1.1541x over previous
//
#include <hip/hip_runtime.h>
#include <math.h>

// Problem constants: N=4, L=2048, E=512, H=8, hd=64, FORECAST=8
// M = N*L = 8192 token rows.

#define NEGV -1e30f

typedef __bf16 bf16_t;
typedef __bf16 bf16x4 __attribute__((ext_vector_type(4)));
typedef __bf16 bf16x8 __attribute__((ext_vector_type(8)));
typedef float f32x4 __attribute__((ext_vector_type(4)));

#define MFMA(a, b, c) __builtin_amdgcn_mfma_f32_16x16x32_bf16((a), (b), (c), 0, 0, 0)

// 0.125 * log2(e): folded into Q so scores are already in log2 domain.
#define QSCALE 0.18033688011112042f

// Swizzled LDS access for [*][64]-bf16 tiles (row stride 128 B):
// byte = r*128 + (colbyte ^ ((r&7)<<4)).  Applied on BOTH write and read
// (fattn K/V), or on read-only when the source was PRE-swizzled (GEMMs).
__device__ __forceinline__ bf16x8* swz_ptr(bf16_t* base, int r, int cb) {
  return (bf16x8*)((char*)base + r * 128 + (cb ^ ((r & 7) << 4)));
}
__device__ __forceinline__ const bf16x8* swz_cptr(const bf16_t* base, int r, int cb) {
  return (const bf16x8*)((const char*)base + r * 128 + (cb ^ ((r & 7) << 4)));
}

// async global->LDS, 16 B per lane. LDS dest is wave-uniform base + lane*16;
// global src is per-lane.
__device__ __forceinline__ void gload16(const bf16_t* g, bf16_t* l) {
  __builtin_amdgcn_global_load_lds(
      (const __attribute__((address_space(1))) void*)g,
      (__attribute__((address_space(3))) void*)l, 16, 0, 0);
}

// Pre-swizzle: logical col c (0..63) of a row r stored at:
//   c' = (c & 7) | 8*(((c>>3) ^ (r & 7)) & 7)   [within each 64-col k-block]

// ---------------------------------------------------------------------------
// xconv: Xb[s][k] = bf16(X[s][k]), PRE-SWIZZLED within 64-col k-blocks.
// ---------------------------------------------------------------------------
__global__ __launch_bounds__(256) void xconv(const float* __restrict__ X,
                                             bf16_t* __restrict__ Xb) {
  const int gid = blockIdx.x * 256 + threadIdx.x;
  const int s = gid >> 6, j = gid & 63;  // j: 8-elem block index within row
  const float4* src = (const float4*)(X + (size_t)s * 512 + j * 8);
  const float4 f0 = src[0], f1 = src[1];
  bf16x8 v;
  v[0] = (bf16_t)f0.x; v[1] = (bf16_t)f0.y; v[2] = (bf16_t)f0.z; v[3] = (bf16_t)f0.w;
  v[4] = (bf16_t)f1.x; v[5] = (bf16_t)f1.y; v[6] = (bf16_t)f1.z; v[7] = (bf16_t)f1.w;
  *(bf16x8*)&Xb[(size_t)s * 512 + (j >> 3) * 64 + 8 * ((j & 7) ^ (s & 7))] = v;
}

// ---------------------------------------------------------------------------
// wconv: WT[n][k] = bf16(Wqkv[k][n]), transposed + PRE-SWIZZLED.
// grid (24 n-tiles, 8 k-tiles).
// ---------------------------------------------------------------------------
__global__ __launch_bounds__(256) void wconv(const float* __restrict__ W,
                                             bf16_t* __restrict__ WT) {
  const int n0 = blockIdx.x * 64, k0 = blockIdx.y * 64;
  __shared__ float Wf[64][65];
  const int tid = threadIdx.x;
#pragma unroll
  for (int c = 0; c < 16; ++c) {
    const int idx = tid + c * 256;
    const int kk = idx >> 6, nn = idx & 63;
    Wf[kk][nn] = W[(size_t)(k0 + kk) * 1536 + n0 + nn];
  }
  __syncthreads();
  const int nr = tid >> 2;
  const int jb = (tid & 3) * 2;
#pragma unroll
  for (int t = 0; t < 2; ++t) {
    const int j = jb + t;
    bf16x8 v;
#pragma unroll
    for (int i = 0; i < 8; ++i) v[i] = (bf16_t)Wf[j * 8 + i][nr];
    *(bf16x8*)&WT[(size_t)(n0 + nr) * 512 + k0 + 8 * (j ^ (nr & 7))] = v;
  }
}

// ---------------------------------------------------------------------------
// build_powers: per head h, P = I + (Xi - Xi^T); pows[h][n] = P^(n+1), f32.
// ---------------------------------------------------------------------------
__global__ __launch_bounds__(256) void build_powers(const float* __restrict__ Xi,
                                                    float* __restrict__ pows) {
  const int h = blockIdx.x;
  __shared__ __align__(16) float P[64][68];
  __shared__ __align__(16) float cur[64][68];
  const int tid = threadIdx.x;
  const float* xi = Xi + (size_t)h * 4096;
  float* dst = pows + (size_t)h * 8 * 4096;
  for (int idx = tid; idx < 4096; idx += 256) {
    const int i = idx >> 6, j = idx & 63;
    const float p = (i == j ? 1.f : 0.f) + xi[i * 64 + j] - xi[j * 64 + i];
    P[i][j] = p;
    cur[i][j] = p;
    dst[idx] = p;  // n=0 -> P^1
  }
  __syncthreads();
  const int i = tid >> 2;
  const int j0 = (tid & 3) * 16;
  for (int n = 1; n < 8; ++n) {
    float a[16];
#pragma unroll
    for (int jj = 0; jj < 16; ++jj) a[jj] = 0.f;
    for (int dd = 0; dd < 64; ++dd) {
      const float c = cur[i][dd];
#pragma unroll
      for (int jj = 0; jj < 16; ++jj) a[jj] += c * P[dd][j0 + jj];
    }
    __syncthreads();
#pragma unroll
    for (int jj = 0; jj < 16; ++jj) {
      cur[i][j0 + jj] = a[jj];
      dst[n * 4096 + i * 64 + j0 + jj] = a[jj];
    }
    __syncthreads();
  }
}

// ---------------------------------------------------------------------------
// build_B: BmatT[n][e][(h*64+d)] = sum_dd pows[h][n][d][dd] * Wo[h*64+dd][e]
// Output TRANSPOSED [e][k] and PRE-SWIZZLED within each head's 64-col block.
// grid (4 e-tiles, 8 n, 8 h).
// ---------------------------------------------------------------------------
__global__ __launch_bounds__(256) void build_B(const float* __restrict__ pows,
                                               const float* __restrict__ Wo,
                                               bf16_t* __restrict__ BmatT) {
  const int et = blockIdx.x;
  const int n = blockIdx.y;
  const int h = blockIdx.z;
  __shared__ __align__(16) float P[64][68];
  __shared__ __align__(16) float We[64][128];
  const int tid = threadIdx.x;
  const float* src = pows + ((size_t)h * 8 + n) * 4096;
  for (int idx = tid; idx < 4096; idx += 256) P[idx >> 6][idx & 63] = src[idx];
  const int e0 = et * 128;
  for (int idx = tid; idx < 8192; idx += 256) {
    const int dd = idx >> 7, e = idx & 127;
    We[dd][e] = Wo[(size_t)(h * 64 + dd) * 512 + e0 + e];
  }
  __syncthreads();
  const int d = tid >> 2;
  const int eq = (tid & 3) * 32;  // multiple of 32 -> (e&7) == (j&7)
  float acc[32];
#pragma unroll
  for (int j = 0; j < 32; ++j) acc[j] = 0.f;
  for (int dd = 0; dd < 64; ++dd) {
    const float p = P[d][dd];
#pragma unroll
    for (int j = 0; j < 32; ++j) acc[j] += p * We[dd][eq + j];
  }
  bf16_t* dst = BmatT + (size_t)n * 512 * 512 + (size_t)(e0 + eq) * 512 + h * 64;
  const int dlo = d & 7, dhi = d >> 3;
#pragma unroll
  for (int j = 0; j < 32; ++j)
    dst[(size_t)j * 512 + 8 * (dhi ^ (j & 7)) + dlo] = (bf16_t)acc[j];
}

// ---------------------------------------------------------------------------
// qkv_gemm: qkv = X @ Wqkv + bqkv; A=Xb (pre-swizzled bf16), B=WT (transposed,
// pre-swizzled bf16). global_load_lds staging, linear LDS, swizzled reads.
// Scatter epilogue:
//   q -> qw [b][h][s][64] bf16, PRE-SCALED by 0.125*log2(e)
//   k -> kw [b][h][s][64] bf16
//   v -> vt [b][h][64][s] bf16 (TRANSPOSED, d-major)
// ---------------------------------------------------------------------------
__global__ __launch_bounds__(256) void qkv_gemm(const bf16_t* __restrict__ Xb,
                                                const bf16_t* __restrict__ WT,
                                                const float* __restrict__ bias,
                                                bf16_t* __restrict__ qw,
                                                bf16_t* __restrict__ kw,
                                                bf16_t* __restrict__ vt) {
  __shared__ __align__(16) bf16_t As[128 * 64];
  __shared__ __align__(16) bf16_t Bs[128 * 64];
  const int tid = threadIdx.x;
  const int wave = tid >> 6, lane = tid & 63;
  const int g = lane >> 4, li = lane & 15;
  const int row0 = blockIdx.x * 128;
  const int col0 = blockIdx.y * 128;
  const int wm = (wave >> 1) * 64, wn = (wave & 1) * 64;
  f32x4 acc[4][4] = {};
  const bf16_t* asrc = Xb + (size_t)(row0 + wave * 32 + (lane >> 3)) * 512 + (lane & 7) * 8;
  const bf16_t* bsrc = WT + (size_t)(col0 + wave * 32 + (lane >> 3)) * 512 + (lane & 7) * 8;
  bf16_t* adst = &As[wave * 32 * 64];
  bf16_t* bdst = &Bs[wave * 32 * 64];
  for (int k0 = 0; k0 < 512; k0 += 64) {
#pragma unroll
    for (int c = 0; c < 4; ++c) {
      gload16(asrc + (size_t)c * 8 * 512 + k0, adst + c * 512);
      gload16(bsrc + (size_t)c * 8 * 512 + k0, bdst + c * 512);
    }
    __syncthreads();
#pragma unroll
    for (int ks = 0; ks < 2; ++ks) {
      bf16x8 af[4], bfr[4];
#pragma unroll
      for (int mr = 0; mr < 4; ++mr)
        af[mr] = *swz_cptr(As, wm + mr * 16 + li, ks * 64 + g * 16);
#pragma unroll
      for (int nr = 0; nr < 4; ++nr)
        bfr[nr] = *swz_cptr(Bs, wn + nr * 16 + li, ks * 64 + g * 16);
#pragma unroll
      for (int mr = 0; mr < 4; ++mr)
#pragma unroll
        for (int nr = 0; nr < 4; ++nr)
          acc[mr][nr] = MFMA(af[mr], bfr[nr], acc[mr][nr]);
    }
    __syncthreads();
  }
  // epilogue
  const int cbase = col0 + wn;            // multiple of 64
  const int sel = cbase >> 9;             // 0=q 1=k 2=v (uniform per wave)
  const int hh = (cbase & 511) >> 6;      // head (uniform per wave)
  const int bb = row0 >> 11;              // batch (uniform per block)
  const size_t hb = (size_t)(bb * 8 + hh) * (2048 * 64);
  if (sel == 2) {
    // v: transposed store vt[d][s], packed bf16x4 along s
    bf16_t* vbase = vt + hb;
#pragma unroll
    for (int nr = 0; nr < 4; ++nr) {
      const int dcol = nr * 16 + li;
      const float bv = bias[cbase + dcol];
#pragma unroll
      for (int mr = 0; mr < 4; ++mr) {
        bf16x4 pk;
#pragma unroll
        for (int i = 0; i < 4; ++i) pk[i] = (bf16_t)(acc[mr][nr][i] + bv);
        const int s = (row0 + wm + mr * 16 + g * 4) & 2047;
        *(bf16x4*)&vbase[(size_t)dcol * 2048 + s] = pk;
      }
    }
  } else {
    bf16_t* dstp = (sel == 0 ? qw : kw) + hb;
    const float sc = (sel == 0) ? QSCALE : 1.0f;
#pragma unroll
    for (int nr = 0; nr < 4; ++nr) {
      const int dcol = nr * 16 + li;
      const float bv = bias[cbase + dcol];
#pragma unroll
      for (int mr = 0; mr < 4; ++mr) {
#pragma unroll
        for (int i = 0; i < 4; ++i) {
          const int r = row0 + wm + mr * 16 + g * 4 + i;
          const int s = r & 2047;
          dstp[(size_t)s * 64 + dcol] = (bf16_t)((acc[mr][nr][i] + bv) * sc);
        }
      }
    }
  }
}

// ---------------------------------------------------------------------------
// fattn: causal flash attention, SWAPPED-OPERAND layout (unchanged from r5
// except the attn epilogue stores PRE-SWIZZLED for out_gemm's gload_lds).
// ---------------------------------------------------------------------------
__global__ __launch_bounds__(256, 4) void fattn(const bf16_t* __restrict__ qw,
                                                const bf16_t* __restrict__ kw,
                                                const bf16_t* __restrict__ vt,
                                                bf16_t* __restrict__ attn) {
  __shared__ __align__(16) bf16_t Ks[2][64][64];
  __shared__ __align__(16) bf16_t Vs[2][64][64];  // rows = d, cols = key
  __shared__ __align__(16) bf16_t Ps[4][16][64];  // wave-private P^T source, swizzled
  const int tid = threadIdx.x;
  const int w = tid >> 6;
  const int lane = tid & 63;
  const int g = lane >> 4;
  const int li = lane & 15;
  const int qt = (int)gridDim.x - 1 - (int)blockIdx.x;  // longest blocks first
  const int h = blockIdx.y;
  const int b = blockIdx.z;
  const size_t base = ((size_t)(b * 8 + h)) * (2048 * 64);
  const int q0 = qt * 64;
  const int qrow = q0 + w * 16 + li;  // this lane's q-row
  const bf16x8 aq0 = *(const bf16x8*)(qw + base + (size_t)qrow * 64 + g * 8);
  const bf16x8 aq1 = *(const bf16x8*)(qw + base + (size_t)qrow * 64 + 32 + g * 8);
  const bf16_t* kbase = kw + base;
  const bf16_t* vbase = vt + base;  // [64][2048]
  const int r_st = tid >> 2;  // staging row 0..63
  const int qu = tid & 3;     // staging quarter
  // prologue: stage tile 0 into buffer 0 (swizzled)
  {
    const bf16_t* kp = kbase + (size_t)r_st * 64 + qu * 16;
    const bf16_t* vp = vbase + (size_t)r_st * 2048 + qu * 16;
    *swz_ptr(&Ks[0][0][0], r_st, qu * 32) = *(const bf16x8*)kp;
    *swz_ptr(&Ks[0][0][0], r_st, qu * 32 + 16) = *(const bf16x8*)(kp + 8);
    *swz_ptr(&Vs[0][0][0], r_st, qu * 32) = *(const bf16x8*)vp;
    *swz_ptr(&Vs[0][0][0], r_st, qu * 32 + 16) = *(const bf16x8*)(vp + 8);
  }
  f32x4 accO[4] = {};  // accO[nt][i] = O^T: q=li, d = nt*16 + g*4 + i
  float m_run = -__builtin_inff();
  float l_run = 0.f;
  // P-row LDS addressing (wave-private, swizzled by (li&7))
  char* const psrow = (char*)&Ps[w][li][0];
  const int pswz = (li & 7) << 4;
  for (int kt = 0; kt <= qt; ++kt) {
    __syncthreads();  // buf[cur] fully staged; previous compute done
    const int cur = kt & 1;
    const bool pf = kt < qt;
    // T14: issue next tile's global loads now; they land during the MFMA phase
    bf16x8 nk0, nk1, nv0, nv1;
    if (pf) {
      const int kb2 = (kt + 1) * 64;
      const bf16_t* kp = kbase + (size_t)(kb2 + r_st) * 64 + qu * 16;
      const bf16_t* vp = vbase + (size_t)r_st * 2048 + kb2 + qu * 16;
      nk0 = *(const bf16x8*)kp;
      nk1 = *(const bf16x8*)(kp + 8);
      nv0 = *(const bf16x8*)vp;
      nv1 = *(const bf16x8*)(vp + 8);
    }
    // S^T tile: sv[nt][i] = S[q = li][key = kb + nt*16 + g*4 + i]
    f32x4 sv[4];
    __builtin_amdgcn_s_setprio(1);
#pragma unroll
    for (int nt = 0; nt < 4; ++nt) {
      const bf16x8 bk0 = *swz_cptr(&Ks[cur][0][0], nt * 16 + li, g * 16);
      const bf16x8 bk1 = *swz_cptr(&Ks[cur][0][0], nt * 16 + li, 64 + g * 16);
      f32x4 z = {0.f, 0.f, 0.f, 0.f};
      z = MFMA(bk0, aq0, z);
      sv[nt] = MFMA(bk1, aq1, z);
    }
    __builtin_amdgcn_s_setprio(0);
    if (kt == qt) {  // diagonal tile mask: key > q-row
#pragma unroll
      for (int nt = 0; nt < 4; ++nt)
#pragma unroll
        for (int i = 0; i < 4; ++i)
          if (nt * 16 + g * 4 + i > w * 16 + li) sv[nt][i] = NEGV;
    }
    // row max: 15 in-lane + 2 shuffles
    float pmax = sv[0][0];
#pragma unroll
    for (int nt = 0; nt < 4; ++nt)
#pragma unroll
      for (int i = 0; i < 4; ++i) pmax = fmaxf(pmax, sv[nt][i]);
    pmax = fmaxf(pmax, __shfl_xor(pmax, 16, 64));
    pmax = fmaxf(pmax, __shfl_xor(pmax, 32, 64));
    // T13 defer-max: only rescale when max grew by > 8 (log2 domain)
    if (!__all(pmax - m_run <= 8.f)) {
      const float newm = fmaxf(m_run, pmax);
      const float sc = exp2f(m_run - newm);
      l_run *= sc;
      m_run = newm;
#pragma unroll
      for (int nt = 0; nt < 4; ++nt)
#pragma unroll
        for (int i = 0; i < 4; ++i) accO[nt][i] *= sc;
    }
    // P = exp2(S - m), in-lane sum + 2 shuffles
    float rsum = 0.f;
#pragma unroll
    for (int nt = 0; nt < 4; ++nt) {
#pragma unroll
      for (int i = 0; i < 4; ++i) {
        const float p = exp2f(sv[nt][i] - m_run);
        sv[nt][i] = p;
        rsum += p;
      }
    }
    rsum += __shfl_xor(rsum, 16, 64);
    rsum += __shfl_xor(rsum, 32, 64);
    l_run += rsum;
    // P -> wave-private LDS, packed bf16x4, XOR-swizzled (4 x ds_write_b64)
#pragma unroll
    for (int nt = 0; nt < 4; ++nt) {
      bf16x4 pk;
#pragma unroll
      for (int i = 0; i < 4; ++i) pk[i] = (bf16_t)sv[nt][i];
      *(bf16x4*)(psrow + ((nt * 32 + g * 8) ^ pswz)) = pk;
    }
    const bf16x8 ap0 = *(const bf16x8*)(psrow + ((g * 16) ^ pswz));
    const bf16x8 ap1 = *(const bf16x8*)(psrow + ((64 + g * 16) ^ pswz));
    // O^T += V^T * P^T
    __builtin_amdgcn_s_setprio(1);
#pragma unroll
    for (int nt = 0; nt < 4; ++nt) {
      const bf16x8 bv0 = *swz_cptr(&Vs[cur][0][0], nt * 16 + li, g * 16);
      const bf16x8 bv1 = *swz_cptr(&Vs[cur][0][0], nt * 16 + li, 64 + g * 16);
      accO[nt] = MFMA(bv0, ap0, accO[nt]);
      accO[nt] = MFMA(bv1, ap1, accO[nt]);
    }
    __builtin_amdgcn_s_setprio(0);
    // write next tile's staged regs into the other buffer (before next barrier)
    if (pf) {
      *swz_ptr(&Ks[cur ^ 1][0][0], r_st, qu * 32) = nk0;
      *swz_ptr(&Ks[cur ^ 1][0][0], r_st, qu * 32 + 16) = nk1;
      *swz_ptr(&Vs[cur ^ 1][0][0], r_st, qu * 32) = nv0;
      *swz_ptr(&Vs[cur ^ 1][0][0], r_st, qu * 32 + 16) = nv1;
    }
  }
  // epilogue: PRE-SWIZZLED store for out_gemm:
  //   logical col c = nt*16 + g*4 within this head's 64-block,
  //   stored block = (c>>3) ^ (row&7), row&7 = li&7.
  {
    const float inv = 1.0f / l_run;
    bf16_t* arow = attn + (size_t)(b * 2048 + qrow) * 512 + h * 64;
#pragma unroll
    for (int nt = 0; nt < 4; ++nt) {
      bf16x4 pk;
#pragma unroll
      for (int i = 0; i < 4; ++i) pk[i] = (bf16_t)(accO[nt][i] * inv);
      *(bf16x4*)&arow[8 * ((nt * 2 + (g >> 1)) ^ (li & 7)) + (g & 1) * 4] = pk;
    }
  }
}

// ---------------------------------------------------------------------------
// out_gemm: out[b][nf][s][:] = attn_cat[b*2048+s][:] @ B[nf] + bo, f32 out.
// A = attn (pre-swizzled), B = BmatT (transposed, pre-swizzled).
// global_load_lds staging, linear LDS, swizzled reads.
// grid (64 m-tiles, 4 col-tiles, 8 forecast)
// ---------------------------------------------------------------------------
__global__ __launch_bounds__(256) void out_gemm(const bf16_t* __restrict__ A,
                                                const bf16_t* __restrict__ BmatT,
                                                const float* __restrict__ bo,
                                                float* __restrict__ out) {
  __shared__ __align__(16) bf16_t As[128 * 64];
  __shared__ __align__(16) bf16_t Bs[128 * 64];
  const int tid = threadIdx.x;
  const int wave = tid >> 6, lane = tid & 63;
  const int g = lane >> 4, li = lane & 15;
  const int row0 = blockIdx.x * 128;
  const int col0 = blockIdx.y * 128;
  const int nf = blockIdx.z;
  const int wm = (wave >> 1) * 64, wn = (wave & 1) * 64;
  f32x4 acc[4][4] = {};
  const bf16_t* asrc = A + (size_t)(row0 + wave * 32 + (lane >> 3)) * 512 + (lane & 7) * 8;
  const bf16_t* bsrc = BmatT + (size_t)nf * 512 * 512 +
                       (size_t)(col0 + wave * 32 + (lane >> 3)) * 512 + (lane & 7) * 8;
  bf16_t* adst = &As[wave * 32 * 64];
  bf16_t* bdst = &Bs[wave * 32 * 64];
  for (int k0 = 0; k0 < 512; k0 += 64) {
#pragma unroll
    for (int c = 0; c < 4; ++c) {
      gload16(asrc + (size_t)c * 8 * 512 + k0, adst + c * 512);
      gload16(bsrc + (size_t)c * 8 * 512 + k0, bdst + c * 512);
    }
    __syncthreads();
#pragma unroll
    for (int ks = 0; ks < 2; ++ks) {
      bf16x8 af[4], bfr[4];
#pragma unroll
      for (int mr = 0; mr < 4; ++mr)
        af[mr] = *swz_cptr(As, wm + mr * 16 + li, ks * 64 + g * 16);
#pragma unroll
      for (int nr = 0; nr < 4; ++nr)
        bfr[nr] = *swz_cptr(Bs, wn + nr * 16 + li, ks * 64 + g * 16);
#pragma unroll
      for (int mr = 0; mr < 4; ++mr)
#pragma unroll
        for (int nr = 0; nr < 4; ++nr)
          acc[mr][nr] = MFMA(af[mr], bfr[nr], acc[mr][nr]);
    }
    __syncthreads();
  }
  const int bb = row0 >> 11;
  float* obase = out + ((size_t)(bb * 8 + nf)) * (2048 * 512);
#pragma unroll
  for (int nr = 0; nr < 4; ++nr) {
    const int c = col0 + wn + nr * 16 + li;
    const float bv = bo[c];
#pragma unroll
    for (int mr = 0; mr < 4; ++mr) {
#pragma unroll
      for (int i = 0; i < 4; ++i) {
        const int r = row0 + wm + mr * 16 + g * 4 + i;
        const int s = r & 2047;
        obase[(size_t)s * 512 + c] = acc[mr][nr][i] + bv;
      }
    }
  }
}

// ---------------------------------------------------------------------------
extern "C" void kernel_launch(void* const* d_in, const int* in_sizes, int n_in,
                              void* d_out, int out_size, void* d_ws, size_t ws_size,
                              hipStream_t stream) {
  const float* query = (const float*)d_in[0];
  // d_in[1]=key, d_in[2]=value are unused by the reference forward.
  const float* Wqkv = (const float*)d_in[3];
  const float* bqkv = (const float*)d_in[4];
  const float* Wo = (const float*)d_in[5];
  const float* bo = (const float*)d_in[6];
  const float* Xi = (const float*)d_in[7];
  float* out = (float*)d_out;

  char* ws = (char*)d_ws;
  bf16_t* qw = (bf16_t*)(ws + 0);                 // [4][8][2048][64] bf16 = 8 MiB (pre-scaled)
  bf16_t* kw = (bf16_t*)(ws + 8388608);           // 8 MiB
  bf16_t* vt = (bf16_t*)(ws + 16777216);          // [4][8][64][2048] bf16 = 8 MiB (transposed)
  // Xb and attn SHARE this region: Xb consumed by qkv_gemm, then fattn
  // overwrites it with attn (sequential stream order makes this safe).
  bf16_t* Xb = (bf16_t*)(ws + 25165824);          // [8192][512] bf16 = 8 MiB (pre-swizzled)
  bf16_t* attn = (bf16_t*)(ws + 25165824);        // [8192][512] bf16 = 8 MiB (pre-swizzled)
  bf16_t* BmatT = (bf16_t*)(ws + 33554432);       // [8][512][512] bf16 = 4 MiB (T, pre-swizzled)
  float* pows = (float*)(ws + 37748736);          // [8][8][64][64] f32 = 1 MiB
  bf16_t* WT = (bf16_t*)(ws + 38797312);          // [1536][512] bf16 = 1.5 MiB (T, pre-swizzled)

  xconv<<<dim3(2048), dim3(256), 0, stream>>>(query, Xb);
  wconv<<<dim3(24, 8), dim3(256), 0, stream>>>(Wqkv, WT);
  build_powers<<<dim3(8), dim3(256), 0, stream>>>(Xi, pows);
  build_B<<<dim3(4, 8, 8), dim3(256), 0, stream>>>(pows, Wo, BmatT);
  qkv_gemm<<<dim3(64, 12), dim3(256), 0, stream>>>(Xb, WT, bqkv, qw, kw, vt);
  fattn<<<dim3(32, 8, 4), dim3(256), 0, stream>>>(qw, kw, vt, attn);
  out_gemm<<<dim3(64, 4, 8), dim3(256), 0, stream>>>(attn, BmatT, bo, out);
}